// Round 11
// baseline (180.959 us; speedup 1.0000x reference)
//
#include <hip/hip_runtime.h>

#define EPS 1e-10f
#define HALF_LN2PI 0.91893853320467274f
#define LOG2E 1.4426950408889634f

// b=16, win=14, w=6, ww=36, B_T=32, K=3, Bkk=288 (=i), C_T=32, HH=16
// W flat: [i=288][c=32][hr=4][m=4]
// Pt per (bb,p): [i=288][hc=4][m=4] = patchflat[base(p)+m*4+hc], base(p)=(p/6)*96+(p%6)*16
//
// Grid (m/e): 2304 blocks = (blk = bb*36+p)*4 + iq, 128 threads (2 waves).
// Wave handles 36 i: i = iq*72 + wave*36 + t. 9 blocks/CU, 18 waves/CU.
// lane = cl*4+hr; thread covers c in {cl, cl+16}, 4 hc each.
// Mpart[bid][k*64+lane], k: [0..3]=S1a [4..7]=S2a [8..11]=S1b [12..15]=S2b [16]=sRa [17]=sRb
//
// Structure (r10): m0 -> e0 -> m1 -> e1 -> m2 -> out  (6 dispatches).
// e_pass sums the 4 iq Mpart partials itself and computes stats IN REGISTERS
// (f_pass's lane layout == e_pass's lane layout, so no exchange needed);
// m_pass zeroes the denom buffer of the FOLLOWING e_pass (idempotent redundant
// zero-writes, ordered by the dispatch boundary).
//
// Post-mortems encoded here:
//  r6: grid.sync() cooperative fusion = device-scope L2 flush per sync. Dispatch
//      boundaries are the cheap coherence mechanism on MI355X.
//  r7: full unroll of the 36-t loop in m_pass spilled acc[18] -> 1.18 GB scratch
//      writes, 9x regression. m_pass stays at unroll 6, plain bounds.
//  r8: in-loop global stores + atomicAdd share the vmcnt FIFO with W loads.
//      NO global VMEM ops inside t-loops; ap via LDS, epilogue bulk store.
//  r9: hipMemsetAsync = fillBufferAligned dispatch per call -> zero denoms
//      inside a compute kernel instead. Quad-reduce via DPP (VALU, no LDS pipe).
//  r10: f_pass dispatches + stats global round-trip removed (stats recomputed
//      per e-block in registers).

__device__ __forceinline__ float fexp2(float x) {
    float r;
    asm("v_exp_f32 %0, %1" : "=v"(r) : "v"(x));
    return r;
}
// quad-level XOR butterfly adds via DPP (single VALU op each, no LDS pipe)
__device__ __forceinline__ float qxor1_add(float x) {
    float r;
    asm("v_add_f32 %0, %1, %1 quad_perm:[1,0,3,2] row_mask:0xf bank_mask:0xf"
        : "=v"(r) : "v"(x));
    return r;
}
__device__ __forceinline__ float qxor2_add(float x) {
    float r;
    asm("v_add_f32 %0, %1, %1 quad_perm:[2,3,0,1] row_mask:0xf bank_mask:0xf"
        : "=v"(r) : "v"(x));
    return r;
}

template <int IT>
__global__ __launch_bounds__(128)
void m_pass(const float* __restrict__ poses, const float* __restrict__ acts,
            float* __restrict__ Ptg, float* __restrict__ actp,
            const float* __restrict__ W,
            const float* __restrict__ ap_buf, const float* __restrict__ denom_prev,
            float* __restrict__ Mpart, float* __restrict__ denom_zero)
{
    __shared__ __align__(16) float Pt_lds[1152];   // 72 i x 16
    __shared__ float act_lds[72];
    __shared__ float invd_lds[72];
    __shared__ __align__(16) float red[1152];

    const int tid  = threadIdx.x;
    const int wave = tid >> 6, lane = tid & 63;
    const int cl   = lane >> 2;
    const int bid  = blockIdx.x;
    const int blk  = bid >> 2, iq = bid & 3;
    const int bb   = blk / 36, p = blk - bb * 36;
    const int i0   = iq * 72;
    const size_t pbase  = (size_t)blk * 4608;
    const size_t apbase = (size_t)blk * 9216;

    // zero denom for the NEXT e_pass (idempotent: every p-block writes 0).
    if (tid < 72)
        denom_zero[bb * 288 + i0 + tid] = 0.0f;

    if (IT == 0) {
        const int base = (p / 6) * 96 + (p % 6) * 16;
        for (int e = tid; e < 1152; e += 128) {
            int il = e >> 4, j = e & 15;
            int i = i0 + il;
            int hc = j >> 2, m = j & 3;
            int f = base + m * 4 + hc;              // flat (h,s)
            int h = f / 36, sp = f - h * 36;
            int y = sp / 6, x = sp - y * 6;
            int B = i / 9, kk = i - B * 9;
            int ki = kk / 3, kj = kk - ki * 3;
            float v = poses[(size_t)((bb * 512 + h * 32 + B) * 14 + 2 * x + ki) * 14 + 2 * y + kj];
            Pt_lds[e] = v;
            Ptg[pbase + (size_t)i0 * 16 + e] = v;
        }
        const int y = p / 6, x = p - y * 6;
        for (int e = tid; e < 72; e += 128) {
            int i = i0 + e;
            int B = i / 9, kk = i - B * 9;
            int ki = kk / 3, kj = kk - ki * 3;
            float v = acts[(size_t)((bb * 32 + B) * 14 + 2 * x + ki) * 14 + 2 * y + kj];
            act_lds[e] = v;
            actp[blk * 288 + i] = v;
        }
    } else {
        const float4* src = (const float4*)(Ptg + pbase + (size_t)i0 * 16);
        float4* dst = (float4*)Pt_lds;
        for (int e = tid; e < 288; e += 128) dst[e] = src[e];
        for (int e = tid; e < 72; e += 128) {
            act_lds[e]  = actp[blk * 288 + i0 + e];
            invd_lds[e] = 1.0f / (denom_prev[bb * 288 + i0 + e] + EPS);
        }
    }
    __syncthreads();

    float acc[18];
#pragma unroll
    for (int k = 0; k < 18; ++k) acc[k] = 0.f;

    const float* Wt  = W + (size_t)(i0 + wave * 36) * 512 + (lane << 2);
    const float* apc = ap_buf + apbase + (size_t)(i0 + wave * 36) * 32 + cl;

#pragma unroll 6
    for (int t = 0; t < 36; ++t) {
        const int il = wave * 36 + t;
        const float4 wva = *(const float4*)(Wt + (size_t)t * 512);
        const float4 wvb = *(const float4*)(Wt + (size_t)t * 512 + 256);
        float Ra, Rb;
        if (IT == 0) {
            Ra = 1.0f / 32.0f; Rb = 1.0f / 32.0f;
        } else {
            const float inv = invd_lds[il];
            Ra = fmaf(apc[(size_t)t * 32],      inv, EPS);
            Rb = fmaf(apc[(size_t)t * 32 + 16], inv, EPS);
        }
        const float a_in = act_lds[il];
        const float R4a = Ra * a_in, R4b = Rb * a_in;
        acc[16] += R4a; acc[17] += R4b;
#pragma unroll
        for (int hc = 0; hc < 4; ++hc) {
            const float4 pv = *(const float4*)&Pt_lds[il * 16 + hc * 4];
            float Va = wva.x * pv.x + wva.y * pv.y + wva.z * pv.z + wva.w * pv.w;
            float Vb = wvb.x * pv.x + wvb.y * pv.y + wvb.z * pv.z + wvb.w * pv.w;
            acc[hc]      = fmaf(R4a, Va, acc[hc]);
            acc[4 + hc]  = fmaf(R4a * Va, Va, acc[4 + hc]);
            acc[8 + hc]  = fmaf(R4b, Vb, acc[8 + hc]);
            acc[12 + hc] = fmaf(R4b * Vb, Vb, acc[12 + hc]);
        }
    }

    if (wave == 1) {
#pragma unroll
        for (int k = 0; k < 18; ++k) red[lane * 18 + k] = acc[k];
    }
    __syncthreads();
    if (wave == 0) {
        float* mp = Mpart + (size_t)bid * 1152;
#pragma unroll
        for (int k = 0; k < 18; ++k)
            mp[k * 64 + lane] = acc[k] + red[lane * 18 + k];
    }
}

__global__ __launch_bounds__(128)
void e_pass(const float* __restrict__ Ptg, const float* __restrict__ Mpart,
            const float* __restrict__ W, const float* __restrict__ beta_v,
            const float* __restrict__ beta_a, const float* __restrict__ lambda_p,
            float* __restrict__ ap_buf, float* __restrict__ denom_next)
{
    __shared__ __align__(16) float Pt_lds[1152];
    __shared__ __align__(16) float ap_lds[2304];   // 72 i x 32 c

    const int tid  = threadIdx.x;
    const int wave = tid >> 6, lane = tid & 63;
    const int cl   = lane >> 2, hr = lane & 3;
    const int bid  = blockIdx.x;
    const int blk  = bid >> 2, iq = bid & 3;
    const int bb   = blk / 36;
    const int i0   = iq * 72;
    const size_t pbase  = (size_t)blk * 4608;
    const size_t apbase = (size_t)blk * 9216;

    {
        const float4* src = (const float4*)(Ptg + pbase + (size_t)i0 * 16);
        float4* dst = (float4*)Pt_lds;
        for (int e = tid; e < 288; e += 128) dst[e] = src[e];
    }

    // ---- stats computed IN REGISTERS from the 4 iq Mpart partials (r10):
    // f_pass's lane layout == ours, so each thread derives exactly the stats
    // it needs; no LDS exchange, no extra barrier.
    __align__(16) float mua[4], mub[4], na[4], nb[4], ha[4], hb[4];
    float aca, acb;
    {
        const float* mp = Mpart + (size_t)blk * 4608;
        float s[18];
#pragma unroll
        for (int k = 0; k < 18; ++k)
            s[k] = mp[k * 64 + lane] + mp[1152 + k * 64 + lane]
                 + mp[2304 + k * 64 + lane] + mp[3456 + k * 64 + lane];
        const float lam = lambda_p[0];
#pragma unroll
        for (int q = 0; q < 2; ++q) {
            const int c = cl + q * 16;
            const float sR = s[16 + q];
            float ls = 0.f;
#pragma unroll
            for (int hc = 0; hc < 4; ++hc) {
                const float mu = s[q * 8 + hc] / sR;
                float ss = s[q * 8 + 4 + hc] / sR - mu * mu;
                ss = fmaxf(ss, 1e-30f);
                (q ? mub : mua)[hc] = mu;
                (q ? nb : na)[hc] = (-0.5f / ss) * LOG2E;
                (q ? hb : ha)[hc] = (-0.5f * __logf(ss) - HALF_LN2PI) * LOG2E;
                ls += __logf(sqrtf(ss) + EPS);
            }
            ls += __shfl_xor(ls, 1);
            ls += __shfl_xor(ls, 2);
            const float cost = sR * (16.0f * beta_v[c] + ls);
            const float av = 1.0f / (1.0f + __expf(-lam * (beta_a[c] - cost)));
            if (q) acb = av; else aca = av;
        }
    }
    __syncthreads();

    const float* Wt = W + (size_t)(i0 + wave * 36) * 512 + (lane << 2);

    // ---- t-loop: NO global VMEM inside (r8); quad-reduce via DPP (r9) ----
#pragma unroll 6
    for (int t = 0; t < 36; ++t) {
        const int il = wave * 36 + t;
        const float4 wva = *(const float4*)(Wt + (size_t)t * 512);
        const float4 wvb = *(const float4*)(Wt + (size_t)t * 512 + 256);
        float pea = 0.f, peb = 0.f;
#pragma unroll
        for (int hc = 0; hc < 4; ++hc) {
            const float4 pv = *(const float4*)&Pt_lds[il * 16 + hc * 4];
            float Va = wva.x * pv.x + wva.y * pv.y + wva.z * pv.z + wva.w * pv.w;
            float Vb = wvb.x * pv.x + wvb.y * pv.y + wvb.z * pv.z + wvb.w * pv.w;
            float da = Va - mua[hc];
            float db = Vb - mub[hc];
            pea += fexp2(fmaf(da * da, na[hc], ha[hc]));
            peb += fexp2(fmaf(db * db, nb[hc], hb[hc]));
        }
        pea = qxor1_add(pea);
        pea = qxor2_add(pea);
        peb = qxor1_add(peb);
        peb = qxor2_add(peb);
        if (hr == 0) {
            ap_lds[il * 32 + cl]      = aca * pea;   // banks cl / cl+16: conflict-free
            ap_lds[il * 32 + cl + 16] = acb * peb;
        }
    }
    __syncthreads();

    // ---- epilogue: coalesced bulk store of ap + one atomic per i ----
    {
        const float4* s4 = (const float4*)ap_lds;
        float4* d4 = (float4*)(ap_buf + apbase + (size_t)i0 * 32);
        for (int e = tid; e < 576; e += 128) d4[e] = s4[e];
    }
    if (tid < 72) {
        float s = 0.f;
#pragma unroll
        for (int c = 0; c < 32; ++c)
            s += ap_lds[tid * 32 + ((c + tid) & 31)];   // bank-rotated: no conflicts
        atomicAdd(&denom_next[bb * 288 + i0 + tid], s);
    }
}

__global__ __launch_bounds__(64)
void out_pass(const float* __restrict__ Mpart, const float* __restrict__ beta_v,
              const float* __restrict__ beta_a, const float* __restrict__ lambda_p,
              float* __restrict__ d_out)
{
    const int lane = threadIdx.x;
    const int cl = lane >> 2, hr = lane & 3;
    const int blk = blockIdx.x;
    const int bb = blk / 36, p = blk - bb * 36;
    const float* mp = Mpart + (size_t)blk * 4608;

    float s[18];
#pragma unroll
    for (int k = 0; k < 18; ++k)
        s[k] = mp[k * 64 + lane] + mp[1152 + k * 64 + lane]
             + mp[2304 + k * 64 + lane] + mp[3456 + k * 64 + lane];

    const float lam = lambda_p[0];
#pragma unroll
    for (int q = 0; q < 2; ++q) {
        const int c = cl + q * 16;
        const float sR = s[16 + q];
        float ls = 0.f;
#pragma unroll
        for (int hc = 0; hc < 4; ++hc) {
            const float mu = s[q * 8 + hc] / sR;
            float ss = s[q * 8 + 4 + hc] / sR - mu * mu;
            ss = fmaxf(ss, 1e-30f);
            d_out[(size_t)bb * 18432 + (size_t)(c * 36 + p) * 16 + hr * 4 + hc] = mu;
            ls += __logf(sqrtf(ss) + EPS);
        }
        ls += __shfl_xor(ls, 1);
        ls += __shfl_xor(ls, 2);
        const float cost = sR * (16.0f * beta_v[c] + ls);
        const float av = 1.0f / (1.0f + __expf(-lam * (beta_a[c] - cost)));
        if (hr == 0)
            d_out[294912 + (size_t)bb * 1152 + c * 36 + p] = av;
    }
}

extern "C" void kernel_launch(void* const* d_in, const int* in_sizes, int n_in,
                              void* d_out, int out_size, void* d_ws, size_t ws_size,
                              hipStream_t stream)
{
    const float* lambda_p = (const float*)d_in[0];
    const float* poses    = (const float*)d_in[1];
    const float* acts     = (const float*)d_in[2];
    const float* W        = (const float*)d_in[3];
    const float* beta_v   = (const float*)d_in[4];
    const float* beta_a   = (const float*)d_in[5];
    float* out = (float*)d_out;

    float* ws     = (float*)d_ws;
    float* Ptg    = ws;                     // 576*4608 = 2,654,208 floats
    float* actp   = Ptg + 2654208;          // 576*288  =   165,888
    float* ap_buf = actp + 165888;          // 576*9216 = 5,308,416
    float* Mpart  = ap_buf + 5308416;       // 2304*1152 = 2,654,208
    float* denom0 = Mpart + 2654208;        // 4608
    float* denom1 = denom0 + 4608;          // 4608

    // m0 zeroes denom0; e0 fills it; m1 reads denom0, zeroes denom1; e1 fills;
    // m2 reads denom1 (zeroes dead denom0); out_pass writes d_out.
    m_pass<0><<<2304, 128, 0, stream>>>(poses, acts, Ptg, actp, W, ap_buf, denom1, Mpart, denom0);
    e_pass<<<2304, 128, 0, stream>>>(Ptg, Mpart, W, beta_v, beta_a, lambda_p, ap_buf, denom0);
    m_pass<1><<<2304, 128, 0, stream>>>(poses, acts, Ptg, actp, W, ap_buf, denom0, Mpart, denom1);
    e_pass<<<2304, 128, 0, stream>>>(Ptg, Mpart, W, beta_v, beta_a, lambda_p, ap_buf, denom1);
    m_pass<1><<<2304, 128, 0, stream>>>(poses, acts, Ptg, actp, W, ap_buf, denom1, Mpart, denom0);
    out_pass<<<576, 64, 0, stream>>>(Mpart, beta_v, beta_a, lambda_p, out);
}